// Round 6
// baseline (363.254 us; speedup 1.0000x reference)
//
#include <hip/hip_runtime.h>
#include <hip/hip_bf16.h>

#define BSZ   4
#define NSEQ  2048
#define DIMM  1024
#define NHEAD 16
#define HD    64
#define N3    (3*DIMM)
#define MTOK  (BSZ*NSEQ)      // 8192
#define SCALE 0.125f          // 64^-0.5
#define CQ    0.18033688011112042f   // SCALE * log2(e), folded into Q

typedef __attribute__((ext_vector_type(8))) short    short8;
typedef __attribute__((ext_vector_type(4))) short    short4v;
typedef __attribute__((ext_vector_type(2))) unsigned uint2v;
typedef __attribute__((ext_vector_type(8))) __bf16   bf16x8;
typedef __attribute__((ext_vector_type(4))) float    f32x4;

__device__ inline short f2bf(float f) {
    unsigned u = __builtin_bit_cast(unsigned, f);
    u += 0x7fffu + ((u >> 16) & 1u);          // RNE
    return (short)(u >> 16);
}

// pack two fp32 -> two bf16 (round-half-up; differs from RNE only on exact ties)
__device__ inline unsigned pack_bf16(float a, float b) {
    unsigned ua = __builtin_bit_cast(unsigned, a) + 0x8000u;
    unsigned ub = __builtin_bit_cast(unsigned, b) + 0x8000u;
    return __builtin_amdgcn_perm(ub, ua, 0x07060302u);  // lo=a.hi16, hi=b.hi16
}

__device__ inline float fast_exp2(float x) {
#if __has_builtin(__builtin_amdgcn_exp2f)
    return __builtin_amdgcn_exp2f(x);
#else
    return exp2f(x);
#endif
}

__device__ inline bf16x8 lds_frag(const short* p) {
    return __builtin_bit_cast(bf16x8, *(const short8*)p);
}

__device__ inline bf16x8 glb_frag(const short* p) {
    return __builtin_bit_cast(bf16x8, *(const short8*)p);
}

__device__ inline void gld_lds16(const short* g, short* l) {
    __builtin_amdgcn_global_load_lds(
        (const __attribute__((address_space(1))) void*)g,
        (__attribute__((address_space(3))) void*)l, 16, 0, 0);
}

// ---------------------------------------------------------------------------
// Prepass 1: fp32 -> bf16 straight copy (8 elems/thread)
// ---------------------------------------------------------------------------
__global__ __launch_bounds__(256)
void cvt_bf16(const float* __restrict__ src, short* __restrict__ dst, int n8)
{
    int i = blockIdx.x * 256 + threadIdx.x;
    if (i >= n8) return;
    float4 v0 = ((const float4*)src)[i * 2];
    float4 v1 = ((const float4*)src)[i * 2 + 1];
    short8 s = { f2bf(v0.x), f2bf(v0.y), f2bf(v0.z), f2bf(v0.w),
                 f2bf(v1.x), f2bf(v1.y), f2bf(v1.z), f2bf(v1.w) };
    ((short8*)dst)[i] = s;
}

// ---------------------------------------------------------------------------
// Prepass 2: transpose src[K][N] fp32 -> dst[N][K] bf16   (block 32x8)
// ---------------------------------------------------------------------------
__global__ __launch_bounds__(256)
void transpose_bf16(const float* __restrict__ src, short* __restrict__ dst,
                    int K, int N)
{
    __shared__ float tile[32][33];
    const int n0 = blockIdx.x * 32, k0 = blockIdx.y * 32;
    const int tx = threadIdx.x, ty = threadIdx.y;
    #pragma unroll
    for (int i = 0; i < 4; ++i)
        tile[ty + i * 8][tx] = src[(size_t)(k0 + ty + i * 8) * N + n0 + tx];
    __syncthreads();
    #pragma unroll
    for (int i = 0; i < 4; ++i)
        dst[(size_t)(n0 + ty + i * 8) * K + k0 + tx] = f2bf(tile[tx][ty + i * 8]);
}

// ---------------------------------------------------------------------------
// m97-style K-loop body shared by both GEMMs (unchanged)
// ---------------------------------------------------------------------------
#define GEMM_KLOOP(APTR, BPTR)                                                 \
    for (int k0 = 0; k0 < DIMM; k0 += 32) {                                    \
        _Pragma("unroll")                                                      \
        for (int j = 0; j < 2; ++j) {                                          \
            int c = j * 256 + tid;                                             \
            int r = c >> 2, jj = c & 3;                                        \
            int gc = jj ^ ((r >> 1) & 3);                                      \
            gld_lds16(APTR + (size_t)(row0 + r) * DIMM + k0 + gc * 8,          \
                      As + c * 8);                                             \
            gld_lds16(BPTR + (size_t)(col0 + r) * DIMM + k0 + gc * 8,         \
                      Bs + c * 8);                                             \
        }                                                                      \
        __syncthreads();                                                       \
        bf16x8 af[4], bfr[4];                                                  \
        _Pragma("unroll")                                                      \
        for (int mt = 0; mt < 4; ++mt) {                                       \
            int row = wm + mt * 16 + l16;                                      \
            af[mt] = lds_frag(&As[row * 32 + (quad ^ ((row >> 1) & 3)) * 8]);  \
        }                                                                      \
        _Pragma("unroll")                                                      \
        for (int nt = 0; nt < 4; ++nt) {                                       \
            int row = wn + nt * 16 + l16;                                      \
            bfr[nt] = lds_frag(&Bs[row * 32 + (quad ^ ((row >> 1) & 3)) * 8]); \
        }                                                                      \
        _Pragma("unroll")                                                      \
        for (int mt = 0; mt < 4; ++mt)                                         \
            _Pragma("unroll")                                                  \
            for (int nt = 0; nt < 4; ++nt)                                     \
                acc[mt][nt] = __builtin_amdgcn_mfma_f32_16x16x32_bf16(         \
                    af[mt], bfr[nt], acc[mt][nt], 0, 0, 0);                    \
        __syncthreads();                                                       \
    }

// ---------------------------------------------------------------------------
// GEMM1: qkv = xb[8192,1024] @ wqkvT[3072,1024]^T, scatter q/k (row) + v (T)
// Q is pre-scaled by CQ (softmax fold) before its single bf16 rounding.
// ---------------------------------------------------------------------------
__global__ __launch_bounds__(256, 2)
void gemm_qkv(const short* __restrict__ a, const short* __restrict__ bt,
              short* __restrict__ qo, short* __restrict__ ko,
              short* __restrict__ vo)
{
    __shared__ short As[128 * 32];
    __shared__ short Bs[128 * 32];
    const int tid  = threadIdx.x;
    const int wave = tid >> 6, lane = tid & 63;
    const int quad = lane >> 4, l16 = lane & 15;
    const int row0 = blockIdx.x * 128, col0 = blockIdx.y * 128;
    const int wm = (wave >> 1) * 64, wn = (wave & 1) * 64;

    f32x4 acc[4][4] = {};
    GEMM_KLOOP(a, bt)

    #pragma unroll
    for (int mt = 0; mt < 4; ++mt) {
        #pragma unroll
        for (int nt = 0; nt < 4; ++nt) {
            int gcol  = col0 + wn + nt * 16 + l16;
            int which = gcol >> 10;          // 0=q 1=k 2=v
            int cc    = gcol & 1023;
            int h     = cc >> 6, d = cc & 63;
            int growb = row0 + wm + mt * 16 + quad * 4;
            int b_    = growb >> 11;
            int n_    = growb & 2047;
            int bh    = b_ * NHEAD + h;
            if (which == 2) {
                short4v s = { f2bf(acc[mt][nt][0]), f2bf(acc[mt][nt][1]),
                              f2bf(acc[mt][nt][2]), f2bf(acc[mt][nt][3]) };
                *(short4v*)(vo + ((size_t)bh * HD + d) * NSEQ + n_) = s;
            } else if (which == 0) {
                #pragma unroll
                for (int r = 0; r < 4; ++r)
                    qo[((size_t)bh * NSEQ + n_ + r) * HD + d] =
                        f2bf(acc[mt][nt][r] * CQ);
            } else {
                #pragma unroll
                for (int r = 0; r < 4; ++r)
                    ko[((size_t)bh * NSEQ + n_ + r) * HD + d] = f2bf(acc[mt][nt][r]);
            }
        }
    }
}

// ---------------------------------------------------------------------------
// Flash attention v6: cross-tile software pipeline.
// Iter t: barrier -> stage K(t+1) -> issue vf(t-1) loads -> S(t) MFMA ->
// read pf(t-1) into regs -> [PV(t-1) MFMA || exp(t) VALU] -> write P(t).
// pf is pulled into registers before exp overwrites the same LDS (DS ops are
// in-order per wave, P is wave-private) so no P double-buffer is needed.
// q,k: [BH][N][64] bf16; vt: [BH][64][N] bf16; o: [B][N][H*64] bf16
// ---------------------------------------------------------------------------
__global__ __launch_bounds__(256, 3)
void attn(const short* __restrict__ q, const short* __restrict__ k,
          const short* __restrict__ vt, short* __restrict__ o)
{
    __shared__ short Ks[2][64 * 64];      // K tile double buffer, 8 KB each
    __shared__ short Ps[4][32 * 72];      // wave-private P [32 q][64 kv + 8 pad]

    const int tid  = threadIdx.x;
    const int wave = tid >> 6, lane = tid & 63;
    const int quad = lane >> 4, l16 = lane & 15;
    const int bh   = blockIdx.y;
    const int q0   = blockIdx.x * 128;
    const size_t qkbase = (size_t)bh * NSEQ * HD;
    const size_t vbase  = (size_t)bh * HD * NSEQ;
    const int T = NSEQ / 64;

    // Q fragments (B-operand): q row = q0 + wave*32 + g*16 + l16
    bf16x8 qf[2][2];
    #pragma unroll
    for (int g = 0; g < 2; ++g)
        #pragma unroll
        for (int ks = 0; ks < 2; ++ks)
            qf[g][ks] = glb_frag(q + qkbase +
                (size_t)(q0 + wave * 32 + g * 16 + l16) * HD + ks * 32 + quad * 8);

    f32x4 oacc[4][2] = {};                // [ot: d-chunk][g: q-chunk]
    float lsum[2] = {0.f, 0.f};
    short* Pw = &Ps[wave][0];

    // K staging: thread handles chunks tid and 256+tid (rows r, r+32; same xor)
    const int  sr   = tid >> 3, sj = tid & 7;
    const int  soff = sr * HD + ((sj ^ (sr & 7)) * 8);
    const short* kbh = k + qkbase;
    const short* vtb = vt + vbase + (size_t)l16 * NSEQ + quad * 8;

    // prologue: stage tile 0 into buf 0
    gld_lds16(kbh + soff,            &Ks[0][tid * 8]);
    gld_lds16(kbh + soff + 32 * HD,  &Ks[0][2048 + tid * 8]);

    f32x4 sacc[4][2];

    // ---- iteration 0: S(0), exp(0) -> P(0); no PV yet ----
    __syncthreads();                      // K(0) ready
    {
        const short* src = kbh + (size_t)64 * HD;
        gld_lds16(src + soff,           &Ks[1][tid * 8]);
        gld_lds16(src + soff + 32 * HD, &Ks[1][2048 + tid * 8]);
    }
    #pragma unroll
    for (int nt = 0; nt < 4; ++nt)
        #pragma unroll
        for (int g = 0; g < 2; ++g)
            sacc[nt][g] = f32x4{0.f, 0.f, 0.f, 0.f};
    #pragma unroll
    for (int nt = 0; nt < 4; ++nt) {
        int row = nt * 16 + l16;
        #pragma unroll
        for (int ks = 0; ks < 2; ++ks) {
            bf16x8 kf = lds_frag(&Ks[0][row * 64 + (((ks * 4 + quad) ^ (row & 7)) * 8)]);
            #pragma unroll
            for (int g = 0; g < 2; ++g)
                sacc[nt][g] = __builtin_amdgcn_mfma_f32_16x16x32_bf16(
                    kf, qf[g][ks], sacc[nt][g], 0, 0, 0);
        }
    }
    #pragma unroll
    for (int g = 0; g < 2; ++g) {
        #pragma unroll
        for (int nt = 0; nt < 4; ++nt) {
            float p0 = fast_exp2(sacc[nt][g][0]);
            float p1 = fast_exp2(sacc[nt][g][1]);
            float p2 = fast_exp2(sacc[nt][g][2]);
            float p3 = fast_exp2(sacc[nt][g][3]);
            lsum[g] += (p0 + p1) + (p2 + p3);
            uint2v u = { pack_bf16(p0, p1), pack_bf16(p2, p3) };
            *(uint2v*)&Pw[(g * 16 + l16) * 72 + nt * 16 + quad * 4] = u;
        }
    }

    // ---- main loop: iter t does S(t), PV(t-1), exp(t) ----
    for (int t = 1; t < T; ++t) {
        const int kv0  = t * 64;
        __syncthreads();                  // K(t) ready; buf[(t+1)&1] free
        if (t + 1 < T) {
            const short* src = kbh + (size_t)(kv0 + 64) * HD;
            short* dst = &Ks[(t + 1) & 1][0];
            gld_lds16(src + soff,           dst + tid * 8);
            gld_lds16(src + soff + 32 * HD, dst + 2048 + tid * 8);
        }

        // issue V^T fragment loads for tile t-1 (consumed by PV below)
        bf16x8 vf[2][4];
        #pragma unroll
        for (int ks2 = 0; ks2 < 2; ++ks2)
            #pragma unroll
            for (int ot = 0; ot < 4; ++ot)
                vf[ks2][ot] = glb_frag(vtb + (size_t)(ot * 16) * NSEQ +
                                       (kv0 - 64) + ks2 * 32);

        // S(t) from LDS K tile
        const short* Kb = &Ks[t & 1][0];
        f32x4 s2[4][2];
        #pragma unroll
        for (int nt = 0; nt < 4; ++nt)
            #pragma unroll
            for (int g = 0; g < 2; ++g)
                s2[nt][g] = f32x4{0.f, 0.f, 0.f, 0.f};
        #pragma unroll
        for (int nt = 0; nt < 4; ++nt) {
            int row = nt * 16 + l16;
            #pragma unroll
            for (int ks = 0; ks < 2; ++ks) {
                bf16x8 kf = lds_frag(&Kb[row * 64 + (((ks * 4 + quad) ^ (row & 7)) * 8)]);
                #pragma unroll
                for (int g = 0; g < 2; ++g)
                    s2[nt][g] = __builtin_amdgcn_mfma_f32_16x16x32_bf16(
                        kf, qf[g][ks], s2[nt][g], 0, 0, 0);
            }
        }

        // pull P(t-1) fragments into regs BEFORE exp(t) overwrites the LDS
        bf16x8 pf[2][2];
        #pragma unroll
        for (int g = 0; g < 2; ++g)
            #pragma unroll
            for (int ks2 = 0; ks2 < 2; ++ks2)
                pf[g][ks2] = lds_frag(&Pw[(g * 16 + l16) * 72 + ks2 * 32 + quad * 8]);

        // PV(t-1) — independent of exp(t); compiler interleaves MFMA & VALU
        #pragma unroll
        for (int ks2 = 0; ks2 < 2; ++ks2)
            #pragma unroll
            for (int ot = 0; ot < 4; ++ot)
                #pragma unroll
                for (int g = 0; g < 2; ++g)
                    oacc[ot][g] = __builtin_amdgcn_mfma_f32_16x16x32_bf16(
                        vf[ks2][ot], pf[g][ks2], oacc[ot][g], 0, 0, 0);

        // exp(t) -> P(t) into the same wave-private buffer
        #pragma unroll
        for (int g = 0; g < 2; ++g) {
            #pragma unroll
            for (int nt = 0; nt < 4; ++nt) {
                float p0 = fast_exp2(s2[nt][g][0]);
                float p1 = fast_exp2(s2[nt][g][1]);
                float p2 = fast_exp2(s2[nt][g][2]);
                float p3 = fast_exp2(s2[nt][g][3]);
                lsum[g] += (p0 + p1) + (p2 + p3);
                uint2v u = { pack_bf16(p0, p1), pack_bf16(p2, p3) };
                *(uint2v*)&Pw[(g * 16 + l16) * 72 + nt * 16 + quad * 4] = u;
            }
        }
    }

    // ---- tail: PV(T-1) ----
    {
        const int kv0 = (T - 1) * 64;
        bf16x8 vf[2][4];
        #pragma unroll
        for (int ks2 = 0; ks2 < 2; ++ks2)
            #pragma unroll
            for (int ot = 0; ot < 4; ++ot)
                vf[ks2][ot] = glb_frag(vtb + (size_t)(ot * 16) * NSEQ +
                                       kv0 + ks2 * 32);
        bf16x8 pf[2][2];
        #pragma unroll
        for (int g = 0; g < 2; ++g)
            #pragma unroll
            for (int ks2 = 0; ks2 < 2; ++ks2)
                pf[g][ks2] = lds_frag(&Pw[(g * 16 + l16) * 72 + ks2 * 32 + quad * 8]);
        #pragma unroll
        for (int ks2 = 0; ks2 < 2; ++ks2)
            #pragma unroll
            for (int ot = 0; ot < 4; ++ot)
                #pragma unroll
                for (int g = 0; g < 2; ++g)
                    oacc[ot][g] = __builtin_amdgcn_mfma_f32_16x16x32_bf16(
                        vf[ks2][ot], pf[g][ks2], oacc[ot][g], 0, 0, 0);
    }

    // epilogue: combine quad partials of l (2 shuffles), normalize, write
    const int b_ = bh >> 4, h = bh & 15;
    float inv[2];
    #pragma unroll
    for (int g = 0; g < 2; ++g) {
        float l = lsum[g];
        l += __shfl_xor(l, 16);
        l += __shfl_xor(l, 32);
        inv[g] = 1.f / l;
    }
    #pragma unroll
    for (int ot = 0; ot < 4; ++ot) {
        #pragma unroll
        for (int g = 0; g < 2; ++g) {
            short4v s4 = { f2bf(oacc[ot][g][0] * inv[g]),
                           f2bf(oacc[ot][g][1] * inv[g]),
                           f2bf(oacc[ot][g][2] * inv[g]),
                           f2bf(oacc[ot][g][3] * inv[g]) };
            *(short4v*)(o + ((size_t)b_ * NSEQ + q0 + wave * 32 + g * 16 + l16) * DIMM +
                        h * HD + ot * 16 + quad * 4) = s4;
        }
    }
}

// ---------------------------------------------------------------------------
// GEMM2: out = ob[8192,1024](bf16) @ woutT[1024,1024]^T + b_out, fp32 out
// ---------------------------------------------------------------------------
__global__ __launch_bounds__(256, 2)
void gemm_out(const short* __restrict__ a, const short* __restrict__ bt,
              const float* __restrict__ bias, float* __restrict__ out)
{
    __shared__ short As[128 * 32];
    __shared__ short Bs[128 * 32];
    const int tid  = threadIdx.x;
    const int wave = tid >> 6, lane = tid & 63;
    const int quad = lane >> 4, l16 = lane & 15;
    const int row0 = blockIdx.x * 128, col0 = blockIdx.y * 128;
    const int wm = (wave >> 1) * 64, wn = (wave & 1) * 64;

    f32x4 acc[4][4] = {};
    GEMM_KLOOP(a, bt)

    #pragma unroll
    for (int mt = 0; mt < 4; ++mt) {
        #pragma unroll
        for (int nt = 0; nt < 4; ++nt) {
            int gcol = col0 + wn + nt * 16 + l16;
            float bb = bias[gcol];
            #pragma unroll
            for (int r = 0; r < 4; ++r) {
                int grow = row0 + wm + mt * 16 + quad * 4 + r;
                out[(size_t)grow * DIMM + gcol] = acc[mt][nt][r] + bb;
            }
        }
    }
}

// ---------------------------------------------------------------------------
extern "C" void kernel_launch(void* const* d_in, const int* in_sizes, int n_in,
                              void* d_out, int out_size, void* d_ws, size_t ws_size,
                              hipStream_t stream)
{
    const float* x     = (const float*)d_in[0];
    const float* w_qkv = (const float*)d_in[1];
    const float* w_out = (const float*)d_in[2];
    const float* b_out = (const float*)d_in[3];
    float* out = (float*)d_out;

    const size_t per = (size_t)BSZ * NHEAD * NSEQ * HD;  // 8.39M elems
    short* q     = (short*)d_ws;
    short* kk    = q  + per;
    short* v     = kk + per;
    short* xb_ob = v  + per;              // x-bf16, later aliased as attn out
    short* wqkvT = xb_ob + per;           // [3072][1024]
    short* woutT = wqkvT + (size_t)N3 * DIMM;  // [1024][1024]

    cvt_bf16<<<(int)(per / 8 / 256), 256, 0, stream>>>(x, xb_ob, (int)(per / 8));
    transpose_bf16<<<dim3(N3 / 32, DIMM / 32), dim3(32, 8), 0, stream>>>(w_qkv, wqkvT, DIMM, N3);
    transpose_bf16<<<dim3(DIMM / 32, DIMM / 32), dim3(32, 8), 0, stream>>>(w_out, woutT, DIMM, DIMM);

    gemm_qkv<<<dim3(MTOK / 128, N3 / 128), 256, 0, stream>>>(xb_ob, wqkvT, q, kk, v);
    attn<<<dim3(NSEQ / 128, BSZ * NHEAD), 256, 0, stream>>>(q, kk, v, xb_ob);
    gemm_out<<<dim3(MTOK / 128, DIMM / 128), 256, 0, stream>>>(xb_ob, woutT, b_out, out);
}

// Round 7
// 362.248 us; speedup vs baseline: 1.0028x; 1.0028x over previous
//
#include <hip/hip_runtime.h>
#include <hip/hip_bf16.h>

#define BSZ   4
#define NSEQ  2048
#define DIMM  1024
#define NHEAD 16
#define HD    64
#define N3    (3*DIMM)
#define MTOK  (BSZ*NSEQ)      // 8192
#define SCALE 0.125f          // 64^-0.5
#define CQ    0.18033688011112042f   // SCALE * log2(e), folded into Q

typedef __attribute__((ext_vector_type(8))) short    short8;
typedef __attribute__((ext_vector_type(4))) short    short4v;
typedef __attribute__((ext_vector_type(2))) unsigned uint2v;
typedef __attribute__((ext_vector_type(8))) __bf16   bf16x8;
typedef __attribute__((ext_vector_type(4))) float    f32x4;

__device__ inline short f2bf(float f) {
    unsigned u = __builtin_bit_cast(unsigned, f);
    u += 0x7fffu + ((u >> 16) & 1u);          // RNE
    return (short)(u >> 16);
}

// pack two fp32 -> two bf16 (round-half-up; differs from RNE only on exact ties)
__device__ inline unsigned pack_bf16(float a, float b) {
    unsigned ua = __builtin_bit_cast(unsigned, a) + 0x8000u;
    unsigned ub = __builtin_bit_cast(unsigned, b) + 0x8000u;
    return __builtin_amdgcn_perm(ub, ua, 0x07060302u);  // lo=a.hi16, hi=b.hi16
}

__device__ inline float fast_exp2(float x) {
#if __has_builtin(__builtin_amdgcn_exp2f)
    return __builtin_amdgcn_exp2f(x);
#else
    return exp2f(x);
#endif
}

__device__ inline bf16x8 lds_frag(const short* p) {
    return __builtin_bit_cast(bf16x8, *(const short8*)p);
}

__device__ inline bf16x8 glb_frag(const short* p) {
    return __builtin_bit_cast(bf16x8, *(const short8*)p);
}

__device__ inline void gld_lds16(const short* g, short* l) {
    __builtin_amdgcn_global_load_lds(
        (const __attribute__((address_space(1))) void*)g,
        (__attribute__((address_space(3))) void*)l, 16, 0, 0);
}

// ---------------------------------------------------------------------------
// Prepass 1: fp32 -> bf16 straight copy (8 elems/thread)
// ---------------------------------------------------------------------------
__global__ __launch_bounds__(256)
void cvt_bf16(const float* __restrict__ src, short* __restrict__ dst, int n8)
{
    int i = blockIdx.x * 256 + threadIdx.x;
    if (i >= n8) return;
    float4 v0 = ((const float4*)src)[i * 2];
    float4 v1 = ((const float4*)src)[i * 2 + 1];
    short8 s = { f2bf(v0.x), f2bf(v0.y), f2bf(v0.z), f2bf(v0.w),
                 f2bf(v1.x), f2bf(v1.y), f2bf(v1.z), f2bf(v1.w) };
    ((short8*)dst)[i] = s;
}

// ---------------------------------------------------------------------------
// Prepass 2: transpose src[K][N] fp32 -> dst[N][K] bf16   (block 32x8)
// ---------------------------------------------------------------------------
__global__ __launch_bounds__(256)
void transpose_bf16(const float* __restrict__ src, short* __restrict__ dst,
                    int K, int N)
{
    __shared__ float tile[32][33];
    const int n0 = blockIdx.x * 32, k0 = blockIdx.y * 32;
    const int tx = threadIdx.x, ty = threadIdx.y;
    #pragma unroll
    for (int i = 0; i < 4; ++i)
        tile[ty + i * 8][tx] = src[(size_t)(k0 + ty + i * 8) * N + n0 + tx];
    __syncthreads();
    #pragma unroll
    for (int i = 0; i < 4; ++i)
        dst[(size_t)(n0 + ty + i * 8) * K + k0 + tx] = f2bf(tile[tx][ty + i * 8]);
}

// ---------------------------------------------------------------------------
// m97-style K-loop body shared by gemm_qkv (unchanged)
// ---------------------------------------------------------------------------
#define GEMM_KLOOP(APTR, BPTR)                                                 \
    for (int k0 = 0; k0 < DIMM; k0 += 32) {                                    \
        _Pragma("unroll")                                                      \
        for (int j = 0; j < 2; ++j) {                                          \
            int c = j * 256 + tid;                                             \
            int r = c >> 2, jj = c & 3;                                        \
            int gc = jj ^ ((r >> 1) & 3);                                      \
            gld_lds16(APTR + (size_t)(row0 + r) * DIMM + k0 + gc * 8,          \
                      As + c * 8);                                             \
            gld_lds16(BPTR + (size_t)(col0 + r) * DIMM + k0 + gc * 8,         \
                      Bs + c * 8);                                             \
        }                                                                      \
        __syncthreads();                                                       \
        bf16x8 af[4], bfr[4];                                                  \
        _Pragma("unroll")                                                      \
        for (int mt = 0; mt < 4; ++mt) {                                       \
            int row = wm + mt * 16 + l16;                                      \
            af[mt] = lds_frag(&As[row * 32 + (quad ^ ((row >> 1) & 3)) * 8]);  \
        }                                                                      \
        _Pragma("unroll")                                                      \
        for (int nt = 0; nt < 4; ++nt) {                                       \
            int row = wn + nt * 16 + l16;                                      \
            bfr[nt] = lds_frag(&Bs[row * 32 + (quad ^ ((row >> 1) & 3)) * 8]); \
        }                                                                      \
        _Pragma("unroll")                                                      \
        for (int mt = 0; mt < 4; ++mt)                                         \
            _Pragma("unroll")                                                  \
            for (int nt = 0; nt < 4; ++nt)                                     \
                acc[mt][nt] = __builtin_amdgcn_mfma_f32_16x16x32_bf16(         \
                    af[mt], bfr[nt], acc[mt][nt], 0, 0, 0);                    \
        __syncthreads();                                                       \
    }

// ---------------------------------------------------------------------------
// GEMM1: qkv = xb[8192,1024] @ wqkvT[3072,1024]^T, scatter q/k (row) + v (T)
// Q is pre-scaled by CQ (softmax fold) before its single bf16 rounding.
// ---------------------------------------------------------------------------
__global__ __launch_bounds__(256, 2)
void gemm_qkv(const short* __restrict__ a, const short* __restrict__ bt,
              short* __restrict__ qo, short* __restrict__ ko,
              short* __restrict__ vo)
{
    __shared__ short As[128 * 32];
    __shared__ short Bs[128 * 32];
    const int tid  = threadIdx.x;
    const int wave = tid >> 6, lane = tid & 63;
    const int quad = lane >> 4, l16 = lane & 15;
    const int row0 = blockIdx.x * 128, col0 = blockIdx.y * 128;
    const int wm = (wave >> 1) * 64, wn = (wave & 1) * 64;

    f32x4 acc[4][4] = {};
    GEMM_KLOOP(a, bt)

    #pragma unroll
    for (int mt = 0; mt < 4; ++mt) {
        #pragma unroll
        for (int nt = 0; nt < 4; ++nt) {
            int gcol  = col0 + wn + nt * 16 + l16;
            int which = gcol >> 10;          // 0=q 1=k 2=v
            int cc    = gcol & 1023;
            int h     = cc >> 6, d = cc & 63;
            int growb = row0 + wm + mt * 16 + quad * 4;
            int b_    = growb >> 11;
            int n_    = growb & 2047;
            int bh    = b_ * NHEAD + h;
            if (which == 2) {
                short4v s = { f2bf(acc[mt][nt][0]), f2bf(acc[mt][nt][1]),
                              f2bf(acc[mt][nt][2]), f2bf(acc[mt][nt][3]) };
                *(short4v*)(vo + ((size_t)bh * HD + d) * NSEQ + n_) = s;
            } else if (which == 0) {
                #pragma unroll
                for (int r = 0; r < 4; ++r)
                    qo[((size_t)bh * NSEQ + n_ + r) * HD + d] =
                        f2bf(acc[mt][nt][r] * CQ);
            } else {
                #pragma unroll
                for (int r = 0; r < 4; ++r)
                    ko[((size_t)bh * NSEQ + n_ + r) * HD + d] = f2bf(acc[mt][nt][r]);
            }
        }
    }
}

// ---------------------------------------------------------------------------
// Flash attention v5d: exact round-5 structure (146 us proven), with Ps on a
// 64-short stride + 16B-chunk XOR swizzle (chunk ^= l16&7) instead of +8 pad.
// LDS 34.8 -> 32.0 KB. Write: 2-way (free); read: conflict-free.
// q,k: [BH][N][64] bf16; vt: [BH][64][N] bf16; o: [B][N][H*64] bf16
// ---------------------------------------------------------------------------
__global__ __launch_bounds__(256, 3)
void attn(const short* __restrict__ q, const short* __restrict__ k,
          const short* __restrict__ vt, short* __restrict__ o)
{
    __shared__ short Ks[2][64 * 64];      // K tile double buffer, 8 KB each
    __shared__ short Ps[4][32 * 64];      // wave-private P [32 q][64 kv], swizzled

    const int tid  = threadIdx.x;
    const int wave = tid >> 6, lane = tid & 63;
    const int quad = lane >> 4, l16 = lane & 15;
    const int bh   = blockIdx.y;
    const int q0   = blockIdx.x * 128;
    const size_t qkbase = (size_t)bh * NSEQ * HD;
    const size_t vbase  = (size_t)bh * HD * NSEQ;

    // Q fragments (B-operand): q row = q0 + wave*32 + g*16 + l16
    bf16x8 qf[2][2];
    #pragma unroll
    for (int g = 0; g < 2; ++g)
        #pragma unroll
        for (int ks = 0; ks < 2; ++ks)
            qf[g][ks] = glb_frag(q + qkbase +
                (size_t)(q0 + wave * 32 + g * 16 + l16) * HD + ks * 32 + quad * 8);

    f32x4 oacc[4][2] = {};                // [ot: d-chunk][g: q-chunk]
    float lsum[2] = {0.f, 0.f};
    short* Pw = &Ps[wave][0];
    const int psw = l16 & 7;              // P chunk swizzle key (row & 7)

    // K staging: thread handles chunks tid and 256+tid (rows r, r+32; same xor)
    const int  sr   = tid >> 3, sj = tid & 7;
    const int  soff = sr * HD + ((sj ^ (sr & 7)) * 8);
    const short* kbh = k + qkbase;

    // prologue: stage tile 0 into buf 0
    gld_lds16(kbh + soff,            &Ks[0][tid * 8]);
    gld_lds16(kbh + soff + 32 * HD,  &Ks[0][2048 + tid * 8]);

    for (int t = 0; t < NSEQ / 64; ++t) {
        const int kv0 = t * 64;
        __syncthreads();                  // buf[t&1] ready; buf[~t&1] free
        if (t + 1 < NSEQ / 64) {
            const short* src = kbh + (size_t)(kv0 + 64) * HD;
            short* dst = &Ks[(t + 1) & 1][0];
            gld_lds16(src + soff,           dst + tid * 8);
            gld_lds16(src + soff + 32 * HD, dst + 2048 + tid * 8);
        }
        const short* Kb = &Ks[t & 1][0];

        // hoist V^T fragment loads: L2 latency hides under S-MFMA + softmax
        bf16x8 vf[2][4];
        #pragma unroll
        for (int ks2 = 0; ks2 < 2; ++ks2)
            #pragma unroll
            for (int ot = 0; ot < 4; ++ot)
                vf[ks2][ot] = glb_frag(vt + vbase +
                    (size_t)(ot * 16 + l16) * NSEQ + kv0 + ks2 * 32 + quad * 8);

        // S^T: kv = nt*16 + quad*4 + r (row), q = g*16 + l16 (col)
        f32x4 sacc[4][2] = {};
        #pragma unroll
        for (int nt = 0; nt < 4; ++nt) {
            int row = nt * 16 + l16;
            #pragma unroll
            for (int ks = 0; ks < 2; ++ks) {
                bf16x8 kf = lds_frag(&Kb[row * 64 + (((ks * 4 + quad) ^ (row & 7)) * 8)]);
                #pragma unroll
                for (int g = 0; g < 2; ++g)
                    sacc[nt][g] = __builtin_amdgcn_mfma_f32_16x16x32_bf16(
                        kf, qf[g][ks], sacc[nt][g], 0, 0, 0);
            }
        }

        // max-free softmax: p = exp2(s); per-lane l partial; packed bf16 store
        // P write: 8 B at chunk c = nt*2+(quad>>1), half = quad&1, c ^= psw
        #pragma unroll
        for (int g = 0; g < 2; ++g) {
            #pragma unroll
            for (int nt = 0; nt < 4; ++nt) {
                float p0 = fast_exp2(sacc[nt][g][0]);
                float p1 = fast_exp2(sacc[nt][g][1]);
                float p2 = fast_exp2(sacc[nt][g][2]);
                float p3 = fast_exp2(sacc[nt][g][3]);
                lsum[g] += (p0 + p1) + (p2 + p3);
                uint2v u = { pack_bf16(p0, p1), pack_bf16(p2, p3) };
                int pc = (nt * 2 + (quad >> 1)) ^ psw;
                *(uint2v*)&Pw[(g * 16 + l16) * 64 + pc * 8 + (quad & 1) * 4] = u;
            }
        }

        // O^T += V^T P : A = V^T chunk (regs), B = P (wave-private LDS)
        // P read: 16 B chunk c = ks2*4+quad, c ^= psw
        #pragma unroll
        for (int ks2 = 0; ks2 < 2; ++ks2) {
            bf16x8 pf[2];
            #pragma unroll
            for (int g = 0; g < 2; ++g)
                pf[g] = lds_frag(&Pw[(g * 16 + l16) * 64 +
                                     (((ks2 * 4 + quad) ^ psw) * 8)]);
            #pragma unroll
            for (int ot = 0; ot < 4; ++ot)
                #pragma unroll
                for (int g = 0; g < 2; ++g)
                    oacc[ot][g] = __builtin_amdgcn_mfma_f32_16x16x32_bf16(
                        vf[ks2][ot], pf[g], oacc[ot][g], 0, 0, 0);
        }
    }

    // epilogue: combine quad partials of l (2 shuffles), normalize, write
    const int b_ = bh >> 4, h = bh & 15;
    float inv[2];
    #pragma unroll
    for (int g = 0; g < 2; ++g) {
        float l = lsum[g];
        l += __shfl_xor(l, 16);
        l += __shfl_xor(l, 32);
        inv[g] = 1.f / l;
    }
    #pragma unroll
    for (int ot = 0; ot < 4; ++ot) {
        #pragma unroll
        for (int g = 0; g < 2; ++g) {
            short4v s4 = { f2bf(oacc[ot][g][0] * inv[g]),
                           f2bf(oacc[ot][g][1] * inv[g]),
                           f2bf(oacc[ot][g][2] * inv[g]),
                           f2bf(oacc[ot][g][3] * inv[g]) };
            *(short4v*)(o + ((size_t)b_ * NSEQ + q0 + wave * 32 + g * 16 + l16) * DIMM +
                        h * HD + ot * 16 + quad * 4) = s4;
        }
    }
}

// ---------------------------------------------------------------------------
// GEMM2: out = ob[8192,1024](bf16) @ woutT[1024,1024]^T + b_out, fp32 out
// Re-tiled 64x128 (grid 128x8 = 1024 blocks -> 4 blocks/CU; old 512 = 2/CU).
// Wave w: rows (w&1)*32 + mt*16, cols (w>>1)*64 + nt*16; acc[2][4].
// ---------------------------------------------------------------------------
__global__ __launch_bounds__(256, 3)
void gemm_out(const short* __restrict__ a, const short* __restrict__ bt,
              const float* __restrict__ bias, float* __restrict__ out)
{
    __shared__ short As[64 * 32];
    __shared__ short Bs[128 * 32];
    const int tid  = threadIdx.x;
    const int wave = tid >> 6, lane = tid & 63;
    const int quad = lane >> 4, l16 = lane & 15;
    const int row0 = blockIdx.x * 64, col0 = blockIdx.y * 128;
    const int wm = (wave & 1) * 32, wn = (wave >> 1) * 64;

    f32x4 acc[2][4] = {};

    for (int k0 = 0; k0 < DIMM; k0 += 32) {
        {   // A: 64x32 = 256 16B-chunks, 1 per thread
            int r = tid >> 2, jj = tid & 3;
            int gc = jj ^ ((r >> 1) & 3);
            gld_lds16(a + (size_t)(row0 + r) * DIMM + k0 + gc * 8, As + tid * 8);
        }
        #pragma unroll
        for (int j = 0; j < 2; ++j) {   // B: 128x32 = 512 chunks
            int c = j * 256 + tid;
            int r = c >> 2, jj = c & 3;
            int gc = jj ^ ((r >> 1) & 3);
            gld_lds16(bt + (size_t)(col0 + r) * DIMM + k0 + gc * 8, Bs + c * 8);
        }
        __syncthreads();
        bf16x8 af[2], bfr[4];
        #pragma unroll
        for (int mt = 0; mt < 2; ++mt) {
            int row = wm + mt * 16 + l16;
            af[mt] = lds_frag(&As[row * 32 + (quad ^ ((row >> 1) & 3)) * 8]);
        }
        #pragma unroll
        for (int nt = 0; nt < 4; ++nt) {
            int row = wn + nt * 16 + l16;
            bfr[nt] = lds_frag(&Bs[row * 32 + (quad ^ ((row >> 1) & 3)) * 8]);
        }
        #pragma unroll
        for (int mt = 0; mt < 2; ++mt)
            #pragma unroll
            for (int nt = 0; nt < 4; ++nt)
                acc[mt][nt] = __builtin_amdgcn_mfma_f32_16x16x32_bf16(
                    af[mt], bfr[nt], acc[mt][nt], 0, 0, 0);
        __syncthreads();
    }

    #pragma unroll
    for (int mt = 0; mt < 2; ++mt) {
        #pragma unroll
        for (int nt = 0; nt < 4; ++nt) {
            int gcol = col0 + wn + nt * 16 + l16;
            float bb = bias[gcol];
            #pragma unroll
            for (int r = 0; r < 4; ++r) {
                int grow = row0 + wm + mt * 16 + quad * 4 + r;
                out[(size_t)grow * DIMM + gcol] = acc[mt][nt][r] + bb;
            }
        }
    }
}

// ---------------------------------------------------------------------------
extern "C" void kernel_launch(void* const* d_in, const int* in_sizes, int n_in,
                              void* d_out, int out_size, void* d_ws, size_t ws_size,
                              hipStream_t stream)
{
    const float* x     = (const float*)d_in[0];
    const float* w_qkv = (const float*)d_in[1];
    const float* w_out = (const float*)d_in[2];
    const float* b_out = (const float*)d_in[3];
    float* out = (float*)d_out;

    const size_t per = (size_t)BSZ * NHEAD * NSEQ * HD;  // 8.39M elems
    short* q     = (short*)d_ws;
    short* kk    = q  + per;
    short* v     = kk + per;
    short* xb_ob = v  + per;              // x-bf16, later aliased as attn out
    short* wqkvT = xb_ob + per;           // [3072][1024]
    short* woutT = wqkvT + (size_t)N3 * DIMM;  // [1024][1024]

    cvt_bf16<<<(int)(per / 8 / 256), 256, 0, stream>>>(x, xb_ob, (int)(per / 8));
    transpose_bf16<<<dim3(N3 / 32, DIMM / 32), dim3(32, 8), 0, stream>>>(w_qkv, wqkvT, DIMM, N3);
    transpose_bf16<<<dim3(DIMM / 32, DIMM / 32), dim3(32, 8), 0, stream>>>(w_out, woutT, DIMM, DIMM);

    gemm_qkv<<<dim3(MTOK / 128, N3 / 128), 256, 0, stream>>>(xb_ob, wqkvT, q, kk, v);
    attn<<<dim3(NSEQ / 128, BSZ * NHEAD), 256, 0, stream>>>(q, kk, v, xb_ob);
    gemm_out<<<dim3(MTOK / 64, DIMM / 128), 256, 0, stream>>>(xb_ob, woutT, b_out, out);
}

// Round 8
// 319.584 us; speedup vs baseline: 1.1366x; 1.1335x over previous
//
#include <hip/hip_runtime.h>
#include <hip/hip_bf16.h>

#define BSZ   4
#define NSEQ  2048
#define DIMM  1024
#define NHEAD 16
#define HD    64
#define N3    (3*DIMM)
#define MTOK  (BSZ*NSEQ)      // 8192
#define SCALE 0.125f          // 64^-0.5
#define CQ    0.18033688011112042f   // SCALE * log2(e), folded into Q

typedef __attribute__((ext_vector_type(8))) short    short8;
typedef __attribute__((ext_vector_type(4))) short    short4v;
typedef __attribute__((ext_vector_type(2))) unsigned uint2v;
typedef __attribute__((ext_vector_type(8))) __bf16   bf16x8;
typedef __attribute__((ext_vector_type(4))) float    f32x4;

__device__ inline short f2bf(float f) {
    unsigned u = __builtin_bit_cast(unsigned, f);
    u += 0x7fffu + ((u >> 16) & 1u);          // RNE
    return (short)(u >> 16);
}

// pack two fp32 -> two bf16 (round-half-up; differs from RNE only on exact ties)
__device__ inline unsigned pack_bf16(float a, float b) {
    unsigned ua = __builtin_bit_cast(unsigned, a) + 0x8000u;
    unsigned ub = __builtin_bit_cast(unsigned, b) + 0x8000u;
    return __builtin_amdgcn_perm(ub, ua, 0x07060302u);  // lo=a.hi16, hi=b.hi16
}

__device__ inline float fast_exp2(float x) {
#if __has_builtin(__builtin_amdgcn_exp2f)
    return __builtin_amdgcn_exp2f(x);
#else
    return exp2f(x);
#endif
}

__device__ inline bf16x8 lds_frag(const short* p) {
    return __builtin_bit_cast(bf16x8, *(const short8*)p);
}

__device__ inline bf16x8 glb_frag(const short* p) {
    return __builtin_bit_cast(bf16x8, *(const short8*)p);
}

__device__ inline void gld_lds16(const short* g, short* l) {
    __builtin_amdgcn_global_load_lds(
        (const __attribute__((address_space(1))) void*)g,
        (__attribute__((address_space(3))) void*)l, 16, 0, 0);
}

// ---------------------------------------------------------------------------
// Prepass 1: fp32 -> bf16 straight copy (8 elems/thread)
// ---------------------------------------------------------------------------
__global__ __launch_bounds__(256)
void cvt_bf16(const float* __restrict__ src, short* __restrict__ dst, int n8)
{
    int i = blockIdx.x * 256 + threadIdx.x;
    if (i >= n8) return;
    float4 v0 = ((const float4*)src)[i * 2];
    float4 v1 = ((const float4*)src)[i * 2 + 1];
    short8 s = { f2bf(v0.x), f2bf(v0.y), f2bf(v0.z), f2bf(v0.w),
                 f2bf(v1.x), f2bf(v1.y), f2bf(v1.z), f2bf(v1.w) };
    ((short8*)dst)[i] = s;
}

// ---------------------------------------------------------------------------
// Prepass 2: transpose src[K][N] fp32 -> dst[N][K] bf16   (block 32x8)
// ---------------------------------------------------------------------------
__global__ __launch_bounds__(256)
void transpose_bf16(const float* __restrict__ src, short* __restrict__ dst,
                    int K, int N)
{
    __shared__ float tile[32][33];
    const int n0 = blockIdx.x * 32, k0 = blockIdx.y * 32;
    const int tx = threadIdx.x, ty = threadIdx.y;
    #pragma unroll
    for (int i = 0; i < 4; ++i)
        tile[ty + i * 8][tx] = src[(size_t)(k0 + ty + i * 8) * N + n0 + tx];
    __syncthreads();
    #pragma unroll
    for (int i = 0; i < 4; ++i)
        dst[(size_t)(n0 + ty + i * 8) * K + k0 + tx] = f2bf(tile[tx][ty + i * 8]);
}

// ---------------------------------------------------------------------------
// m97-style K-loop body shared by gemm_qkv (unchanged)
// ---------------------------------------------------------------------------
#define GEMM_KLOOP(APTR, BPTR)                                                 \
    for (int k0 = 0; k0 < DIMM; k0 += 32) {                                    \
        _Pragma("unroll")                                                      \
        for (int j = 0; j < 2; ++j) {                                          \
            int c = j * 256 + tid;                                             \
            int r = c >> 2, jj = c & 3;                                        \
            int gc = jj ^ ((r >> 1) & 3);                                      \
            gld_lds16(APTR + (size_t)(row0 + r) * DIMM + k0 + gc * 8,          \
                      As + c * 8);                                             \
            gld_lds16(BPTR + (size_t)(col0 + r) * DIMM + k0 + gc * 8,         \
                      Bs + c * 8);                                             \
        }                                                                      \
        __syncthreads();                                                       \
        bf16x8 af[4], bfr[4];                                                  \
        _Pragma("unroll")                                                      \
        for (int mt = 0; mt < 4; ++mt) {                                       \
            int row = wm + mt * 16 + l16;                                      \
            af[mt] = lds_frag(&As[row * 32 + (quad ^ ((row >> 1) & 3)) * 8]);  \
        }                                                                      \
        _Pragma("unroll")                                                      \
        for (int nt = 0; nt < 4; ++nt) {                                       \
            int row = wn + nt * 16 + l16;                                      \
            bfr[nt] = lds_frag(&Bs[row * 32 + (quad ^ ((row >> 1) & 3)) * 8]); \
        }                                                                      \
        _Pragma("unroll")                                                      \
        for (int mt = 0; mt < 4; ++mt)                                         \
            _Pragma("unroll")                                                  \
            for (int nt = 0; nt < 4; ++nt)                                     \
                acc[mt][nt] = __builtin_amdgcn_mfma_f32_16x16x32_bf16(         \
                    af[mt], bfr[nt], acc[mt][nt], 0, 0, 0);                    \
        __syncthreads();                                                       \
    }

// ---------------------------------------------------------------------------
// GEMM1: qkv = xb[8192,1024] @ wqkvT[3072,1024]^T, scatter q/k (row) + v (T)
// Q is pre-scaled by CQ (softmax fold) before its single bf16 rounding.
// ---------------------------------------------------------------------------
__global__ __launch_bounds__(256, 2)
void gemm_qkv(const short* __restrict__ a, const short* __restrict__ bt,
              short* __restrict__ qo, short* __restrict__ ko,
              short* __restrict__ vo)
{
    __shared__ short As[128 * 32];
    __shared__ short Bs[128 * 32];
    const int tid  = threadIdx.x;
    const int wave = tid >> 6, lane = tid & 63;
    const int quad = lane >> 4, l16 = lane & 15;
    const int row0 = blockIdx.x * 128, col0 = blockIdx.y * 128;
    const int wm = (wave >> 1) * 64, wn = (wave & 1) * 64;

    f32x4 acc[4][4] = {};
    GEMM_KLOOP(a, bt)

    #pragma unroll
    for (int mt = 0; mt < 4; ++mt) {
        #pragma unroll
        for (int nt = 0; nt < 4; ++nt) {
            int gcol  = col0 + wn + nt * 16 + l16;
            int which = gcol >> 10;          // 0=q 1=k 2=v
            int cc    = gcol & 1023;
            int h     = cc >> 6, d = cc & 63;
            int growb = row0 + wm + mt * 16 + quad * 4;
            int b_    = growb >> 11;
            int n_    = growb & 2047;
            int bh    = b_ * NHEAD + h;
            if (which == 2) {
                short4v s = { f2bf(acc[mt][nt][0]), f2bf(acc[mt][nt][1]),
                              f2bf(acc[mt][nt][2]), f2bf(acc[mt][nt][3]) };
                *(short4v*)(vo + ((size_t)bh * HD + d) * NSEQ + n_) = s;
            } else if (which == 0) {
                #pragma unroll
                for (int r = 0; r < 4; ++r)
                    qo[((size_t)bh * NSEQ + n_ + r) * HD + d] =
                        f2bf(acc[mt][nt][r] * CQ);
            } else {
                #pragma unroll
                for (int r = 0; r < 4; ++r)
                    ko[((size_t)bh * NSEQ + n_ + r) * HD + d] = f2bf(acc[mt][nt][r]);
            }
        }
    }
}

// ---------------------------------------------------------------------------
// Flash attention v5 (byte-exact round-5 version, 146 us measured):
// Q-split (wave owns 32 q), kv tile 64, max-free softmax, Ps stride 72.
// q,k: [BH][N][64] bf16; vt: [BH][64][N] bf16; o: [B][N][H*64] bf16
// ---------------------------------------------------------------------------
__global__ __launch_bounds__(256, 3)
void attn(const short* __restrict__ q, const short* __restrict__ k,
          const short* __restrict__ vt, short* __restrict__ o)
{
    __shared__ short Ks[2][64 * 64];      // K tile double buffer, 8 KB each
    __shared__ short Ps[4][32 * 72];      // wave-private P [32 q][64 kv + 8 pad]

    const int tid  = threadIdx.x;
    const int wave = tid >> 6, lane = tid & 63;
    const int quad = lane >> 4, l16 = lane & 15;
    const int bh   = blockIdx.y;
    const int q0   = blockIdx.x * 128;
    const size_t qkbase = (size_t)bh * NSEQ * HD;
    const size_t vbase  = (size_t)bh * HD * NSEQ;

    // Q fragments (B-operand): q row = q0 + wave*32 + g*16 + l16
    bf16x8 qf[2][2];
    #pragma unroll
    for (int g = 0; g < 2; ++g)
        #pragma unroll
        for (int ks = 0; ks < 2; ++ks)
            qf[g][ks] = glb_frag(q + qkbase +
                (size_t)(q0 + wave * 32 + g * 16 + l16) * HD + ks * 32 + quad * 8);

    f32x4 oacc[4][2] = {};                // [ot: d-chunk][g: q-chunk]
    float lsum[2] = {0.f, 0.f};
    short* Pw = &Ps[wave][0];

    // K staging: thread handles chunks tid and 256+tid (rows r, r+32; same xor)
    const int  sr   = tid >> 3, sj = tid & 7;
    const int  soff = sr * HD + ((sj ^ (sr & 7)) * 8);
    const short* kbh = k + qkbase;

    // prologue: stage tile 0 into buf 0
    gld_lds16(kbh + soff,            &Ks[0][tid * 8]);
    gld_lds16(kbh + soff + 32 * HD,  &Ks[0][2048 + tid * 8]);

    for (int t = 0; t < NSEQ / 64; ++t) {
        const int kv0 = t * 64;
        __syncthreads();                  // buf[t&1] ready; buf[~t&1] free
        if (t + 1 < NSEQ / 64) {
            const short* src = kbh + (size_t)(kv0 + 64) * HD;
            short* dst = &Ks[(t + 1) & 1][0];
            gld_lds16(src + soff,           dst + tid * 8);
            gld_lds16(src + soff + 32 * HD, dst + 2048 + tid * 8);
        }
        const short* Kb = &Ks[t & 1][0];

        // hoist V^T fragment loads: L2 latency hides under S-MFMA + softmax
        bf16x8 vf[2][4];
        #pragma unroll
        for (int ks2 = 0; ks2 < 2; ++ks2)
            #pragma unroll
            for (int ot = 0; ot < 4; ++ot)
                vf[ks2][ot] = glb_frag(vt + vbase +
                    (size_t)(ot * 16 + l16) * NSEQ + kv0 + ks2 * 32 + quad * 8);

        // S^T: kv = nt*16 + quad*4 + r (row), q = g*16 + l16 (col)
        f32x4 sacc[4][2] = {};
        #pragma unroll
        for (int nt = 0; nt < 4; ++nt) {
            int row = nt * 16 + l16;
            #pragma unroll
            for (int ks = 0; ks < 2; ++ks) {
                bf16x8 kf = lds_frag(&Kb[row * 64 + (((ks * 4 + quad) ^ (row & 7)) * 8)]);
                #pragma unroll
                for (int g = 0; g < 2; ++g)
                    sacc[nt][g] = __builtin_amdgcn_mfma_f32_16x16x32_bf16(
                        kf, qf[g][ks], sacc[nt][g], 0, 0, 0);
            }
        }

        // max-free softmax: p = exp2(s); per-lane l partial; packed bf16 store
        #pragma unroll
        for (int g = 0; g < 2; ++g) {
            #pragma unroll
            for (int nt = 0; nt < 4; ++nt) {
                float p0 = fast_exp2(sacc[nt][g][0]);
                float p1 = fast_exp2(sacc[nt][g][1]);
                float p2 = fast_exp2(sacc[nt][g][2]);
                float p3 = fast_exp2(sacc[nt][g][3]);
                lsum[g] += (p0 + p1) + (p2 + p3);
                uint2v u = { pack_bf16(p0, p1), pack_bf16(p2, p3) };
                *(uint2v*)&Pw[(g * 16 + l16) * 72 + nt * 16 + quad * 4] = u;
            }
        }

        // O^T += V^T P : A = V^T chunk (regs), B = P (wave-private LDS)
        #pragma unroll
        for (int ks2 = 0; ks2 < 2; ++ks2) {
            bf16x8 pf[2];
            #pragma unroll
            for (int g = 0; g < 2; ++g)
                pf[g] = lds_frag(&Pw[(g * 16 + l16) * 72 + ks2 * 32 + quad * 8]);
            #pragma unroll
            for (int ot = 0; ot < 4; ++ot)
                #pragma unroll
                for (int g = 0; g < 2; ++g)
                    oacc[ot][g] = __builtin_amdgcn_mfma_f32_16x16x32_bf16(
                        vf[ks2][ot], pf[g], oacc[ot][g], 0, 0, 0);
        }
    }

    // epilogue: combine quad partials of l (2 shuffles), normalize, write
    const int b_ = bh >> 4, h = bh & 15;
    float inv[2];
    #pragma unroll
    for (int g = 0; g < 2; ++g) {
        float l = lsum[g];
        l += __shfl_xor(l, 16);
        l += __shfl_xor(l, 32);
        inv[g] = 1.f / l;
    }
    #pragma unroll
    for (int ot = 0; ot < 4; ++ot) {
        #pragma unroll
        for (int g = 0; g < 2; ++g) {
            short4v s4 = { f2bf(oacc[ot][g][0] * inv[g]),
                           f2bf(oacc[ot][g][1] * inv[g]),
                           f2bf(oacc[ot][g][2] * inv[g]),
                           f2bf(oacc[ot][g][3] * inv[g]) };
            *(short4v*)(o + ((size_t)b_ * NSEQ + q0 + wave * 32 + g * 16 + l16) * DIMM +
                        h * HD + ot * 16 + quad * 4) = s4;
        }
    }
}

// ---------------------------------------------------------------------------
// GEMM2: out = ob[8192,1024](bf16) @ woutT[1024,1024]^T + b_out, fp32 out
// 64x128 tile (grid 128x8 = 1024 blocks -> 4 blocks/CU).
// ---------------------------------------------------------------------------
__global__ __launch_bounds__(256, 3)
void gemm_out(const short* __restrict__ a, const short* __restrict__ bt,
              const float* __restrict__ bias, float* __restrict__ out)
{
    __shared__ short As[64 * 32];
    __shared__ short Bs[128 * 32];
    const int tid  = threadIdx.x;
    const int wave = tid >> 6, lane = tid & 63;
    const int quad = lane >> 4, l16 = lane & 15;
    const int row0 = blockIdx.x * 64, col0 = blockIdx.y * 128;
    const int wm = (wave & 1) * 32, wn = (wave >> 1) * 64;

    f32x4 acc[2][4] = {};

    for (int k0 = 0; k0 < DIMM; k0 += 32) {
        {   // A: 64x32 = 256 16B-chunks, 1 per thread
            int r = tid >> 2, jj = tid & 3;
            int gc = jj ^ ((r >> 1) & 3);
            gld_lds16(a + (size_t)(row0 + r) * DIMM + k0 + gc * 8, As + tid * 8);
        }
        #pragma unroll
        for (int j = 0; j < 2; ++j) {   // B: 128x32 = 512 chunks
            int c = j * 256 + tid;
            int r = c >> 2, jj = c & 3;
            int gc = jj ^ ((r >> 1) & 3);
            gld_lds16(bt + (size_t)(col0 + r) * DIMM + k0 + gc * 8, Bs + c * 8);
        }
        __syncthreads();
        bf16x8 af[2], bfr[4];
        #pragma unroll
        for (int mt = 0; mt < 2; ++mt) {
            int row = wm + mt * 16 + l16;
            af[mt] = lds_frag(&As[row * 32 + (quad ^ ((row >> 1) & 3)) * 8]);
        }
        #pragma unroll
        for (int nt = 0; nt < 4; ++nt) {
            int row = wn + nt * 16 + l16;
            bfr[nt] = lds_frag(&Bs[row * 32 + (quad ^ ((row >> 1) & 3)) * 8]);
        }
        #pragma unroll
        for (int mt = 0; mt < 2; ++mt)
            #pragma unroll
            for (int nt = 0; nt < 4; ++nt)
                acc[mt][nt] = __builtin_amdgcn_mfma_f32_16x16x32_bf16(
                    af[mt], bfr[nt], acc[mt][nt], 0, 0, 0);
        __syncthreads();
    }

    #pragma unroll
    for (int mt = 0; mt < 2; ++mt) {
        #pragma unroll
        for (int nt = 0; nt < 4; ++nt) {
            int gcol = col0 + wn + nt * 16 + l16;
            float bb = bias[gcol];
            #pragma unroll
            for (int r = 0; r < 4; ++r) {
                int grow = row0 + wm + mt * 16 + quad * 4 + r;
                out[(size_t)grow * DIMM + gcol] = acc[mt][nt][r] + bb;
            }
        }
    }
}

// ---------------------------------------------------------------------------
extern "C" void kernel_launch(void* const* d_in, const int* in_sizes, int n_in,
                              void* d_out, int out_size, void* d_ws, size_t ws_size,
                              hipStream_t stream)
{
    const float* x     = (const float*)d_in[0];
    const float* w_qkv = (const float*)d_in[1];
    const float* w_out = (const float*)d_in[2];
    const float* b_out = (const float*)d_in[3];
    float* out = (float*)d_out;

    const size_t per = (size_t)BSZ * NHEAD * NSEQ * HD;  // 8.39M elems
    short* q     = (short*)d_ws;
    short* kk    = q  + per;
    short* v     = kk + per;
    short* xb_ob = v  + per;              // x-bf16, later aliased as attn out
    short* wqkvT = xb_ob + per;           // [3072][1024]
    short* woutT = wqkvT + (size_t)N3 * DIMM;  // [1024][1024]

    cvt_bf16<<<(int)(per / 8 / 256), 256, 0, stream>>>(x, xb_ob, (int)(per / 8));
    transpose_bf16<<<dim3(N3 / 32, DIMM / 32), dim3(32, 8), 0, stream>>>(w_qkv, wqkvT, DIMM, N3);
    transpose_bf16<<<dim3(DIMM / 32, DIMM / 32), dim3(32, 8), 0, stream>>>(w_out, woutT, DIMM, DIMM);

    gemm_qkv<<<dim3(MTOK / 128, N3 / 128), 256, 0, stream>>>(xb_ob, wqkvT, q, kk, v);
    attn<<<dim3(NSEQ / 128, BSZ * NHEAD), 256, 0, stream>>>(q, kk, v, xb_ob);
    gemm_out<<<dim3(MTOK / 64, DIMM / 128), 256, 0, stream>>>(xb_ob, woutT, b_out, out);
}